// Round 2
// baseline (215.675 us; speedup 1.0000x reference)
//
#include <hip/hip_runtime.h>
#include <hip/hip_bf16.h>

#define B_   4
#define S_   4096
#define DIN  768
#define DH   64

typedef float f32x4 __attribute__((ext_vector_type(4)));
typedef short s16x8 __attribute__((ext_vector_type(8)));
typedef unsigned short u16;

__device__ __forceinline__ u16 f2bf(float f) {
  union { float f; unsigned int u; } a; a.f = f;
  unsigned int u = a.u;
  unsigned int r = (u + 0x7fffu + ((u >> 16) & 1u)) >> 16;  // RNE
  return (u16)r;
}

__device__ __forceinline__ s16x8 ld8s(const u16* p) {
  return *reinterpret_cast<const s16x8*>(p);
}

#define GLD_LDS(gp, lp) \
  __builtin_amdgcn_global_load_lds((const __attribute__((address_space(1))) void*)(gp), \
                                   (__attribute__((address_space(3))) void*)(lp), 16, 0, 0)

// ---------------- kernel 0: W transpose + bf16 + swizzle ----------------
// Wt[n][k], n in [0,192): 0-63 = wq (scaled by 0.125), 64-127 = wk, 128-191 = wv.
// Within each 64-wide k-chunk, 8-element (16B) granules stored at position
// (k/8 & 7) ^ (n & 7)  -> linear global_load_lds staging yields swizzled LDS.
__global__ void prep_w(const float* __restrict__ wq, const float* __restrict__ wk,
                       const float* __restrict__ wv, u16* __restrict__ wt) {
  int tid = blockIdx.x * 256 + threadIdx.x;
  if (tid >= 192 * DIN) return;
  int n = tid / DIN, k = tid % DIN;
  const float* src; float scale = 1.0f; int col;
  if (n < 64)       { src = wq; col = n;       scale = 0.125f; }
  else if (n < 128) { src = wk; col = n - 64;  }
  else              { src = wv; col = n - 128; }
  float v = src[k * DH + col] * scale;
  int chunk = k & ~63;
  int kin = k & 63;
  int gr = (kin >> 3) ^ (n & 7);
  wt[n * DIN + chunk + gr * 8 + (kin & 7)] = f2bf(v);
}

// ---------------- kernel 1: QKV projection GEMM ----------------
// 256 threads (4 waves). Block computes rows m0..m0+63, all 192 cols.
// Outputs: qb/kb row-major [B*S][64] bf16 swizzled; vt transposed [B*64][S] bf16 swizzled.
__global__ __launch_bounds__(256) void qkv_gemm(const float* __restrict__ x,
    const u16* __restrict__ wt, u16* __restrict__ qb, u16* __restrict__ kb,
    u16* __restrict__ vt) {
  __shared__ __align__(16) u16 xlds[64 * 72];   // padded, no conflicts
  __shared__ __align__(16) u16 wlds[192 * 64];  // unpadded (global_load_lds), swizzled
  int t = threadIdx.x;
  int w = t >> 6, l = t & 63, g = l >> 4, lq = l & 15;
  int m0 = blockIdx.x * 64;

  f32x4 acc[12];
#pragma unroll
  for (int i = 0; i < 12; i++) acc[i] = f32x4{0.f, 0.f, 0.f, 0.f};

  for (int ks = 0; ks < 12; ks++) {
    int k0 = ks * 64;
    // stage X (fp32 -> bf16) into padded LDS
#pragma unroll
    for (int i = 0; i < 4; i++) {
      int tau = i * 256 + t;
      int row = tau >> 4, c4 = tau & 15;
      const float4 xv = *reinterpret_cast<const float4*>(
          x + (size_t)(m0 + row) * DIN + k0 + c4 * 4);
      ushort4 hh;
      hh.x = f2bf(xv.x); hh.y = f2bf(xv.y); hh.z = f2bf(xv.z); hh.w = f2bf(xv.w);
      *reinterpret_cast<ushort4*>(&xlds[row * 72 + c4 * 4]) = hh;
    }
    // stage W via 16B global_load_lds (24 chunks of 1024B)
#pragma unroll
    for (int i = 0; i < 6; i++) {
      int tau = i * 4 + w;
      int n = 8 * tau + (l >> 3);
      const u16* src = wt + n * DIN + k0 + (l & 7) * 8;
      GLD_LDS(src, &wlds[tau * 512]);
    }
    asm volatile("s_waitcnt vmcnt(0)" ::: "memory");
    __syncthreads();

    s16x8 a0 = ld8s(&xlds[(16 * w + lq) * 72 + g * 8]);
    s16x8 a1 = ld8s(&xlds[(16 * w + lq) * 72 + g * 8 + 32]);
#pragma unroll
    for (int nt = 0; nt < 12; nt++) {
      int n = nt * 16 + lq;
      s16x8 b0 = ld8s(&wlds[n * 64 + ((g ^ (n & 7)) * 8)]);
      s16x8 b1 = ld8s(&wlds[n * 64 + (((g + 4) ^ (n & 7)) * 8)]);
      acc[nt] = __builtin_amdgcn_mfma_f32_16x16x32_bf16(a0, b0, acc[nt], 0, 0, 0);
      acc[nt] = __builtin_amdgcn_mfma_f32_16x16x32_bf16(a1, b1, acc[nt], 0, 0, 0);
    }
    __syncthreads();
  }

  // epilogue: D layout row=(l>>4)*4+r (+16w), col=lq+16*(nt&3)
  int b = m0 >> 12;
  int srow0 = (m0 & (S_ - 1)) + 16 * w + 4 * g;
#pragma unroll
  for (int nt = 0; nt < 12; nt++) {
    int dcol = (nt & 3) * 16 + lq;
    u16* base = (nt < 4) ? qb : (nt < 8) ? kb : vt;
#pragma unroll
    for (int r = 0; r < 4; r++) {
      int srow = srow0 + r;
      u16 hv = f2bf(acc[nt][r]);
      if (nt < 8) {
        int gr = (dcol >> 3) ^ (srow & 7);
        base[(size_t)(b * S_ + srow) * DH + gr * 8 + (dcol & 7)] = hv;
      } else {
        int gr = ((srow >> 3) & 7) ^ (dcol & 7);
        base[(size_t)(b * DH + dcol) * S_ + (srow & ~63) + gr * 8 + (srow & 7)] = hv;
      }
    }
  }
}

// ---------------- kernel 2: flash attention ----------------
// 256 threads (4 waves). Block = (b, 64 q-rows). Wave w owns q rows 16w..16w+15.
__global__ __launch_bounds__(256) void attn(const u16* __restrict__ qb,
    const u16* __restrict__ kb, const u16* __restrict__ vt, float* __restrict__ out) {
  __shared__ __align__(16) u16 klds[64 * 64];       // swizzled (linear staging)
  __shared__ __align__(16) u16 vlds[64 * 64];       // Vt tile, swizzled
  __shared__ __align__(16) u16 plds[4 * 16 * 72];   // per-wave P, padded

  int t = threadIdx.x;
  int w = t >> 6, l = t & 63, g = l >> 4, lq = l & 15;
  int bq = blockIdx.x;
  int b = bq >> 6;
  int q0 = (bq & 63) * 64;

  // Q fragments in registers (pre-scaled by 0.125 in projection)
  int sq = q0 + 16 * w + lq;
  const u16* qrow = qb + (size_t)(b * S_ + sq) * DH;
  s16x8 qa0 = ld8s(qrow + ((g ^ (sq & 7)) * 8));
  s16x8 qa1 = ld8s(qrow + (((g + 4) ^ (sq & 7)) * 8));

  float mrun[4], lrun[4];
  f32x4 acco[4];
#pragma unroll
  for (int r = 0; r < 4; r++) { mrun[r] = -1e30f; lrun[r] = 0.f; }
#pragma unroll
  for (int nt = 0; nt < 4; nt++) acco[nt] = f32x4{0.f, 0.f, 0.f, 0.f};

  for (int kv = 0; kv < 64; kv++) {
    int k0 = kv * 64;
    // stage K and V tiles (each 8KB, 8 chunks of 1024B)
#pragma unroll
    for (int i = 0; i < 2; i++) {
      int tau = w * 2 + i;
      int row = 8 * tau + (l >> 3);
      const u16* srck = kb + (size_t)(b * S_ + k0 + row) * DH + (l & 7) * 8;
      GLD_LDS(srck, &klds[tau * 512]);
      const u16* srcv = vt + (size_t)(b * DH + row) * S_ + k0 + (l & 7) * 8;
      GLD_LDS(srcv, &vlds[tau * 512]);
    }
    asm volatile("s_waitcnt vmcnt(0)" ::: "memory");
    __syncthreads();

    // S = Q K^T  (D: row=q=4g+r, col=k=kt*16+lq)
    f32x4 accs[4];
#pragma unroll
    for (int kt = 0; kt < 4; kt++) {
      int krow = kt * 16 + lq;
      s16x8 kf0 = ld8s(&klds[krow * 64 + ((g ^ (krow & 7)) * 8)]);
      s16x8 kf1 = ld8s(&klds[krow * 64 + (((g + 4) ^ (krow & 7)) * 8)]);
      f32x4 c = f32x4{0.f, 0.f, 0.f, 0.f};
      c = __builtin_amdgcn_mfma_f32_16x16x32_bf16(qa0, kf0, c, 0, 0, 0);
      c = __builtin_amdgcn_mfma_f32_16x16x32_bf16(qa1, kf1, c, 0, 0, 0);
      accs[kt] = c;
    }

    // online softmax; row r reductions across 16-lane group (k = lane&15)
    float p[4][4];
    float scale[4];
#pragma unroll
    for (int r = 0; r < 4; r++) {
      float mx = fmaxf(fmaxf(accs[0][r], accs[1][r]), fmaxf(accs[2][r], accs[3][r]));
      mx = fmaxf(mx, __shfl_xor(mx, 1));
      mx = fmaxf(mx, __shfl_xor(mx, 2));
      mx = fmaxf(mx, __shfl_xor(mx, 4));
      mx = fmaxf(mx, __shfl_xor(mx, 8));
      float mnew = fmaxf(mrun[r], mx);
      scale[r] = exp2f((mrun[r] - mnew) * 1.44269504f);
      float s = 0.f;
#pragma unroll
      for (int kt = 0; kt < 4; kt++) {
        float pv = exp2f((accs[kt][r] - mnew) * 1.44269504f);
        p[kt][r] = pv; s += pv;
      }
      s += __shfl_xor(s, 1); s += __shfl_xor(s, 2);
      s += __shfl_xor(s, 4); s += __shfl_xor(s, 8);
      lrun[r] = lrun[r] * scale[r] + s;
      mrun[r] = mnew;
    }

    // P -> per-wave LDS (reshape D-layout -> A-fragment layout)
#pragma unroll
    for (int kt = 0; kt < 4; kt++)
#pragma unroll
      for (int r = 0; r < 4; r++)
        plds[w * 1152 + (4 * g + r) * 72 + kt * 16 + lq] = f2bf(p[kt][r]);
    asm volatile("s_waitcnt lgkmcnt(0)" ::: "memory");

    // rescale O accumulator
#pragma unroll
    for (int nt = 0; nt < 4; nt++)
#pragma unroll
      for (int r = 0; r < 4; r++)
        acco[nt][r] *= scale[r];

    // O += P V  (A = P rows q=lq; B = Vt rows d)
    s16x8 pa0 = ld8s(&plds[w * 1152 + lq * 72 + g * 8]);
    s16x8 pa1 = ld8s(&plds[w * 1152 + lq * 72 + g * 8 + 32]);
#pragma unroll
    for (int nt = 0; nt < 4; nt++) {
      int d = nt * 16 + lq;
      s16x8 vf0 = ld8s(&vlds[d * 64 + ((g ^ (d & 7)) * 8)]);
      s16x8 vf1 = ld8s(&vlds[d * 64 + (((g + 4) ^ (d & 7)) * 8)]);
      acco[nt] = __builtin_amdgcn_mfma_f32_16x16x32_bf16(pa0, vf0, acco[nt], 0, 0, 0);
      acco[nt] = __builtin_amdgcn_mfma_f32_16x16x32_bf16(pa1, vf1, acco[nt], 0, 0, 0);
    }
    __syncthreads();
  }

  // normalize + write fp32 output
#pragma unroll
  for (int r = 0; r < 4; r++) {
    float inv = 1.0f / lrun[r];
    int srow = q0 + 16 * w + 4 * g + r;
#pragma unroll
    for (int nt = 0; nt < 4; nt++)
      out[(size_t)(b * S_ + srow) * DH + nt * 16 + lq] = acco[nt][r] * inv;
  }
}

extern "C" void kernel_launch(void* const* d_in, const int* in_sizes, int n_in,
                              void* d_out, int out_size, void* d_ws, size_t ws_size,
                              hipStream_t stream) {
  const float* x  = (const float*)d_in[0];
  const float* wq = (const float*)d_in[1];
  const float* wk = (const float*)d_in[2];
  const float* wv = (const float*)d_in[3];
  float* out = (float*)d_out;
  char* ws = (char*)d_ws;

  u16* wt = (u16*)(ws);                                  // 192*768*2   = 294912 B
  u16* qb = (u16*)(ws + 294912);                         // 16384*64*2  = 2097152 B
  u16* kb = (u16*)(ws + 294912 + 2097152);
  u16* vt = (u16*)(ws + 294912 + 2 * 2097152);           // total ~6.6 MB

  hipLaunchKernelGGL(prep_w,   dim3(576), dim3(256), 0, stream, wq, wk, wv, wt);
  hipLaunchKernelGGL(qkv_gemm, dim3(256), dim3(256), 0, stream, x, wt, qb, kb, vt);
  hipLaunchKernelGGL(attn,     dim3(256), dim3(256), 0, stream, qb, kb, vt, out);
}

// Round 4
// 168.957 us; speedup vs baseline: 1.2765x; 1.2765x over previous
//
#include <hip/hip_runtime.h>
#include <hip/hip_bf16.h>

#define B_   4
#define S_   4096
#define DIN  768
#define DH   64

typedef float f32x4 __attribute__((ext_vector_type(4)));
typedef short s16x8 __attribute__((ext_vector_type(8)));
typedef unsigned short u16;

__device__ __forceinline__ u16 f2bf(float f) {
  union { float f; unsigned int u; } a; a.f = f;
  unsigned int u = a.u;
  unsigned int r = (u + 0x7fffu + ((u >> 16) & 1u)) >> 16;  // RNE
  return (u16)r;
}

__device__ __forceinline__ s16x8 ld8s(const u16* p) {
  return *reinterpret_cast<const s16x8*>(p);
}

__device__ __forceinline__ s16x8 pack8(float4 a, float4 b) {
  s16x8 h;
  h[0] = (short)f2bf(a.x); h[1] = (short)f2bf(a.y);
  h[2] = (short)f2bf(a.z); h[3] = (short)f2bf(a.w);
  h[4] = (short)f2bf(b.x); h[5] = (short)f2bf(b.y);
  h[6] = (short)f2bf(b.z); h[7] = (short)f2bf(b.w);
  return h;
}

#define GLD_LDS(gp, lp) \
  __builtin_amdgcn_global_load_lds((const __attribute__((address_space(1))) void*)(gp), \
                                   (__attribute__((address_space(3))) void*)(lp), 16, 0, 0)

// ---------------- kernel 0: W transpose + bf16 + swizzle ----------------
__global__ void prep_w(const float* __restrict__ wq, const float* __restrict__ wk,
                       const float* __restrict__ wv, u16* __restrict__ wt) {
  int tid = blockIdx.x * 256 + threadIdx.x;
  if (tid >= 192 * DIN) return;
  int n = tid / DIN, k = tid % DIN;
  const float* src; float scale = 1.0f; int col;
  if (n < 64)       { src = wq; col = n;       scale = 0.125f; }
  else if (n < 128) { src = wk; col = n - 64;  }
  else              { src = wv; col = n - 128; }
  float v = src[k * DH + col] * scale;
  int chunk = k & ~63;
  int kin = k & 63;
  int gr = (kin >> 3) ^ (n & 7);
  wt[n * DIN + chunk + gr * 8 + (kin & 7)] = f2bf(v);
}

// ---------------- kernel 1: QKV projection GEMM ----------------
// 512 blocks of 256 thr (4 waves). Block = 32 rows, all 192 cols.
// Wave (wr,wc): rows 16*wr.., cols 96*wc.. ; X/W double-buffered, 1 barrier/iter.
__global__ __launch_bounds__(256) void qkv_gemm(const float* __restrict__ x,
    const u16* __restrict__ wt, u16* __restrict__ qb, u16* __restrict__ kb,
    u16* __restrict__ vt) {
  __shared__ __align__(16) u16 xl[2][32 * 72];
  __shared__ __align__(16) u16 wl[2][192 * 64];
  int t = threadIdx.x;
  int w = t >> 6, l = t & 63, g = l >> 4, lq = l & 15;
  int wr = w >> 1, wc = w & 1;
  int m0 = blockIdx.x * 32;
  int xrow = t >> 3, xc = t & 7;

  f32x4 acc[6];
#pragma unroll
  for (int i = 0; i < 6; i++) acc[i] = f32x4{0.f, 0.f, 0.f, 0.f};

  const float* xp0 = x + (size_t)(m0 + xrow) * DIN + xc * 8;

  // prologue: tile 0
  {
    float4 xa = *reinterpret_cast<const float4*>(xp0);
    float4 xb = *reinterpret_cast<const float4*>(xp0 + 4);
#pragma unroll
    for (int i = 0; i < 6; i++) {
      int tau = i * 4 + w; int n = 8 * tau + (l >> 3);
      GLD_LDS(wt + n * DIN + (l & 7) * 8, &wl[0][tau * 512]);
    }
    *reinterpret_cast<s16x8*>(&xl[0][xrow * 72 + xc * 8]) = pack8(xa, xb);
    asm volatile("s_waitcnt vmcnt(0)" ::: "memory");
    __syncthreads();
  }

  for (int ks = 0; ks < 12; ks++) {
    int cur = ks & 1;
    bool more = ks < 11;
    float4 na, nb;
    if (more) {
      int k1 = (ks + 1) * 64;
      na = *reinterpret_cast<const float4*>(xp0 + k1);
      nb = *reinterpret_cast<const float4*>(xp0 + k1 + 4);
#pragma unroll
      for (int i = 0; i < 6; i++) {
        int tau = i * 4 + w; int n = 8 * tau + (l >> 3);
        GLD_LDS(wt + n * DIN + k1 + (l & 7) * 8, &wl[cur ^ 1][tau * 512]);
      }
    }
    s16x8 a0 = ld8s(&xl[cur][(16 * wr + lq) * 72 + g * 8]);
    s16x8 a1 = ld8s(&xl[cur][(16 * wr + lq) * 72 + g * 8 + 32]);
#pragma unroll
    for (int nt = 0; nt < 6; nt++) {
      int n = wc * 96 + nt * 16 + lq;
      s16x8 b0 = ld8s(&wl[cur][n * 64 + ((g ^ (n & 7)) * 8)]);
      s16x8 b1 = ld8s(&wl[cur][n * 64 + (((g + 4) ^ (n & 7)) * 8)]);
      acc[nt] = __builtin_amdgcn_mfma_f32_16x16x32_bf16(a0, b0, acc[nt], 0, 0, 0);
      acc[nt] = __builtin_amdgcn_mfma_f32_16x16x32_bf16(a1, b1, acc[nt], 0, 0, 0);
    }
    if (more) {
      asm volatile("s_waitcnt vmcnt(0)" ::: "memory");
      *reinterpret_cast<s16x8*>(&xl[cur ^ 1][xrow * 72 + xc * 8]) = pack8(na, nb);
      __syncthreads();
    }
  }

  // epilogue
  int b = m0 >> 12;
  int srow0 = (m0 & (S_ - 1)) + 16 * wr + 4 * g;
#pragma unroll
  for (int nt = 0; nt < 6; nt++) {
    int col = wc * 96 + nt * 16 + lq;
    u16* base; int c;
    if (col < 64)       { base = qb; c = col; }
    else if (col < 128) { base = kb; c = col - 64; }
    else                { base = vt; c = col - 128; }
#pragma unroll
    for (int r = 0; r < 4; r++) {
      int srow = srow0 + r;
      u16 hv = f2bf(acc[nt][r]);
      if (col < 128) {
        int gr = (c >> 3) ^ (srow & 7);
        base[(size_t)(b * S_ + srow) * DH + gr * 8 + (c & 7)] = hv;
      } else {
        int gr = ((srow >> 3) & 7) ^ (c & 7);
        base[(size_t)(b * DH + c) * S_ + (srow & ~63) + gr * 8 + (srow & 7)] = hv;
      }
    }
  }
}

// ---------------- kernel 2: flash attention ----------------
// 256 blocks of 512 thr (8 waves). Waves 0-3: kv 0..2047, waves 4-7: kv 2048..4095.
// Same 64 q-rows per block; double-buffered K/V; in-block softmax merge.
__global__ __launch_bounds__(512) void attn(const u16* __restrict__ qb,
    const u16* __restrict__ kb, const u16* __restrict__ vt, float* __restrict__ out) {
  // smem layout (u16 units):
  //  staging: half*16384 + buf*8192 ; K at +0 (4096), V at +4096   -> 32768 u16 (64KB)
  //  plds:    32768 + w8*1152                                      -> 9216 u16 (18KB)
  __shared__ __align__(16) u16 smem[41984];

  int t = threadIdx.x;
  int w8 = t >> 6, half = w8 >> 2, w = w8 & 3, l = t & 63, g = l >> 4, lq = l & 15;
  int bq = blockIdx.x;
  int b = bq >> 6;
  int q0 = (bq & 63) * 64;
  int kvbase = half * 2048;

  // Q fragments (pre-scaled by 0.125 in projection)
  int sq = q0 + 16 * w + lq;
  const u16* qrow = qb + (size_t)(b * S_ + sq) * DH;
  s16x8 qa0 = ld8s(qrow + ((g ^ (sq & 7)) * 8));
  s16x8 qa1 = ld8s(qrow + (((g + 4) ^ (sq & 7)) * 8));

  u16* pl = smem + 32768 + w8 * 1152;

  float mrun[4], lrun[4];
  f32x4 acco[4];
#pragma unroll
  for (int r = 0; r < 4; r++) { mrun[r] = -1e30f; lrun[r] = 0.f; }
#pragma unroll
  for (int nt = 0; nt < 4; nt++) acco[nt] = f32x4{0.f, 0.f, 0.f, 0.f};

  // staging helper values
  int tau0 = w * 2;
  int srow_st = 8 * tau0 + (l >> 3);   // rows this lane stages (i=0); i=1 adds 8
  int gcol = (l & 7) * 8;

  // prologue: stage tile 0 into buf 0
  {
    u16* dst = smem + half * 16384;
#pragma unroll
    for (int i = 0; i < 2; i++) {
      int row = srow_st + 8 * i;
      GLD_LDS(kb + (size_t)(b * S_ + kvbase + row) * DH + gcol, &dst[(tau0 + i) * 512]);
      GLD_LDS(vt + (size_t)(b * DH + row) * S_ + kvbase + gcol, &dst[4096 + (tau0 + i) * 512]);
    }
    asm volatile("s_waitcnt vmcnt(0)" ::: "memory");
    __syncthreads();
  }

  for (int it = 0; it < 32; it++) {
    int cur = it & 1;
    bool more = it < 31;
    if (more) {
      int k1 = kvbase + (it + 1) * 64;
      u16* dst = smem + half * 16384 + (cur ^ 1) * 8192;
#pragma unroll
      for (int i = 0; i < 2; i++) {
        int row = srow_st + 8 * i;
        GLD_LDS(kb + (size_t)(b * S_ + k1 + row) * DH + gcol, &dst[(tau0 + i) * 512]);
        GLD_LDS(vt + (size_t)(b * DH + row) * S_ + k1 + gcol, &dst[4096 + (tau0 + i) * 512]);
      }
    }
    const u16* kl = smem + half * 16384 + cur * 8192;
    const u16* vl = kl + 4096;

    // S = Q K^T
    f32x4 accs[4];
#pragma unroll
    for (int kt = 0; kt < 4; kt++) {
      int krow = kt * 16 + lq;
      s16x8 kf0 = ld8s(&kl[krow * 64 + ((g ^ (krow & 7)) * 8)]);
      s16x8 kf1 = ld8s(&kl[krow * 64 + (((g + 4) ^ (krow & 7)) * 8)]);
      f32x4 c = f32x4{0.f, 0.f, 0.f, 0.f};
      c = __builtin_amdgcn_mfma_f32_16x16x32_bf16(qa0, kf0, c, 0, 0, 0);
      c = __builtin_amdgcn_mfma_f32_16x16x32_bf16(qa1, kf1, c, 0, 0, 0);
      accs[kt] = c;
    }

    // online softmax (k = lane&15 within 16-lane groups)
    float p[4][4];
    float scale[4];
#pragma unroll
    for (int r = 0; r < 4; r++) {
      float mx = fmaxf(fmaxf(accs[0][r], accs[1][r]), fmaxf(accs[2][r], accs[3][r]));
      mx = fmaxf(mx, __shfl_xor(mx, 1));
      mx = fmaxf(mx, __shfl_xor(mx, 2));
      mx = fmaxf(mx, __shfl_xor(mx, 4));
      mx = fmaxf(mx, __shfl_xor(mx, 8));
      float mnew = fmaxf(mrun[r], mx);
      scale[r] = exp2f((mrun[r] - mnew) * 1.44269504f);
      float s = 0.f;
#pragma unroll
      for (int kt = 0; kt < 4; kt++) {
        float pv = exp2f((accs[kt][r] - mnew) * 1.44269504f);
        p[kt][r] = pv; s += pv;
      }
      s += __shfl_xor(s, 1); s += __shfl_xor(s, 2);
      s += __shfl_xor(s, 4); s += __shfl_xor(s, 8);
      lrun[r] = lrun[r] * scale[r] + s;
      mrun[r] = mnew;
    }

    // P -> per-wave LDS (reshape to A-fragment layout)
#pragma unroll
    for (int kt = 0; kt < 4; kt++)
#pragma unroll
      for (int r = 0; r < 4; r++)
        pl[(4 * g + r) * 72 + kt * 16 + lq] = f2bf(p[kt][r]);
    asm volatile("s_waitcnt lgkmcnt(0)" ::: "memory");

#pragma unroll
    for (int nt = 0; nt < 4; nt++)
#pragma unroll
      for (int r = 0; r < 4; r++)
        acco[nt][r] *= scale[r];

    s16x8 pa0 = ld8s(&pl[lq * 72 + g * 8]);
    s16x8 pa1 = ld8s(&pl[lq * 72 + g * 8 + 32]);
#pragma unroll
    for (int nt = 0; nt < 4; nt++) {
      int d = nt * 16 + lq;
      s16x8 vf0 = ld8s(&vl[d * 64 + ((g ^ (d & 7)) * 8)]);
      s16x8 vf1 = ld8s(&vl[d * 64 + (((g + 4) ^ (d & 7)) * 8)]);
      acco[nt] = __builtin_amdgcn_mfma_f32_16x16x32_bf16(pa0, vf0, acco[nt], 0, 0, 0);
      acco[nt] = __builtin_amdgcn_mfma_f32_16x16x32_bf16(pa1, vf1, acco[nt], 0, 0, 0);
    }
    if (more) {
      asm volatile("s_waitcnt vmcnt(0)" ::: "memory");
      __syncthreads();
    }
  }

  // ---- merge the two kv halves ----
  __syncthreads();                 // all compute done; staging LDS now reusable
  float* mO = reinterpret_cast<float*>(smem);          // 64*64 f32 (16KB)
  float* mM = reinterpret_cast<float*>(smem) + 4096;   // 64
  float* mL = mM + 64;                                 // 64

  if (half == 1) {
#pragma unroll
    for (int nt = 0; nt < 4; nt++)
#pragma unroll
      for (int r = 0; r < 4; r++)
        mO[(16 * w + 4 * g + r) * 64 + nt * 16 + lq] = acco[nt][r];
    if (lq == 0) {
#pragma unroll
      for (int r = 0; r < 4; r++) {
        int row = 16 * w + 4 * g + r;
        mM[row] = mrun[r];
        mL[row] = lrun[r];
      }
    }
  }
  __syncthreads();
  if (half == 0) {
#pragma unroll
    for (int r = 0; r < 4; r++) {
      int row = 16 * w + 4 * g + r;
      float m2 = mM[row], l2 = mL[row];
      float m = fmaxf(mrun[r], m2);
      float f1 = exp2f((mrun[r] - m) * 1.44269504f);
      float f2 = exp2f((m2 - m) * 1.44269504f);
      float inv = 1.0f / (lrun[r] * f1 + l2 * f2);
#pragma unroll
      for (int nt = 0; nt < 4; nt++) {
        float val = (acco[nt][r] * f1 + mO[row * 64 + nt * 16 + lq] * f2) * inv;
        out[(size_t)(b * S_ + q0 + row) * DH + nt * 16 + lq] = val;
      }
    }
  }
}

extern "C" void kernel_launch(void* const* d_in, const int* in_sizes, int n_in,
                              void* d_out, int out_size, void* d_ws, size_t ws_size,
                              hipStream_t stream) {
  const float* x  = (const float*)d_in[0];
  const float* wq = (const float*)d_in[1];
  const float* wk = (const float*)d_in[2];
  const float* wv = (const float*)d_in[3];
  float* out = (float*)d_out;
  char* ws = (char*)d_ws;

  u16* wt = (u16*)(ws);                                  // 294912 B
  u16* qb = (u16*)(ws + 294912);                         // 2097152 B
  u16* kb = (u16*)(ws + 294912 + 2097152);
  u16* vt = (u16*)(ws + 294912 + 2 * 2097152);

  hipLaunchKernelGGL(prep_w,   dim3(576), dim3(256), 0, stream, wq, wk, wv, wt);
  hipLaunchKernelGGL(qkv_gemm, dim3(512), dim3(256), 0, stream, x, wt, qb, kb, vt);
  hipLaunchKernelGGL(attn,     dim3(256), dim3(512), 0, stream, qb, kb, vt, out);
}

// Round 5
// 150.178 us; speedup vs baseline: 1.4361x; 1.1250x over previous
//
#include <hip/hip_runtime.h>
#include <hip/hip_bf16.h>

#define B_   4
#define S_   4096
#define DIN  768
#define DH   64

typedef float f32x4 __attribute__((ext_vector_type(4)));
typedef short s16x8 __attribute__((ext_vector_type(8)));
typedef unsigned short u16;

__device__ __forceinline__ u16 f2bf(float f) {
  union { float f; unsigned int u; } a; a.f = f;
  unsigned int u = a.u;
  unsigned int r = (u + 0x7fffu + ((u >> 16) & 1u)) >> 16;  // RNE
  return (u16)r;
}

// pack two floats to bf16 pair (round-to-nearest, ties away) -> u32
__device__ __forceinline__ unsigned int bfpack2(float a, float b) {
  union { float f; unsigned int u; } ua, ub; ua.f = a; ub.f = b;
  return ((ua.u + 0x8000u) >> 16) | ((ub.u + 0x8000u) & 0xffff0000u);
}

__device__ __forceinline__ s16x8 ld8s(const u16* p) {
  return *reinterpret_cast<const s16x8*>(p);
}

__device__ __forceinline__ s16x8 pack8(float4 a, float4 b) {
  s16x8 h;
  h[0] = (short)f2bf(a.x); h[1] = (short)f2bf(a.y);
  h[2] = (short)f2bf(a.z); h[3] = (short)f2bf(a.w);
  h[4] = (short)f2bf(b.x); h[5] = (short)f2bf(b.y);
  h[6] = (short)f2bf(b.z); h[7] = (short)f2bf(b.w);
  return h;
}

#define GLD_LDS(gp, lp) \
  __builtin_amdgcn_global_load_lds((const __attribute__((address_space(1))) void*)(gp), \
                                   (__attribute__((address_space(3))) void*)(lp), 16, 0, 0)

// ---------------- kernel 0: W transpose + bf16 + swizzle ----------------
__global__ void prep_w(const float* __restrict__ wq, const float* __restrict__ wk,
                       const float* __restrict__ wv, u16* __restrict__ wt) {
  int tid = blockIdx.x * 256 + threadIdx.x;
  if (tid >= 192 * DIN) return;
  int n = tid / DIN, k = tid % DIN;
  const float* src; float scale = 1.0f; int col;
  if (n < 64)       { src = wq; col = n;       scale = 0.125f; }
  else if (n < 128) { src = wk; col = n - 64;  }
  else              { src = wv; col = n - 128; }
  float v = src[k * DH + col] * scale;
  int chunk = k & ~63;
  int kin = k & 63;
  int gr = (kin >> 3) ^ (n & 7);
  wt[n * DIN + chunk + gr * 8 + (kin & 7)] = f2bf(v);
}

// ---------------- kernel 1: QKV projection GEMM ----------------
__global__ __launch_bounds__(256) void qkv_gemm(const float* __restrict__ x,
    const u16* __restrict__ wt, u16* __restrict__ qb, u16* __restrict__ kb,
    u16* __restrict__ vt) {
  __shared__ __align__(16) u16 xl[2][32 * 72];
  __shared__ __align__(16) u16 wl[2][192 * 64];
  int t = threadIdx.x;
  int w = t >> 6, l = t & 63, g = l >> 4, lq = l & 15;
  int wr = w >> 1, wc = w & 1;
  int m0 = blockIdx.x * 32;
  int xrow = t >> 3, xc = t & 7;

  f32x4 acc[6];
#pragma unroll
  for (int i = 0; i < 6; i++) acc[i] = f32x4{0.f, 0.f, 0.f, 0.f};

  const float* xp0 = x + (size_t)(m0 + xrow) * DIN + xc * 8;

  // prologue: tile 0
  {
    float4 xa = *reinterpret_cast<const float4*>(xp0);
    float4 xb = *reinterpret_cast<const float4*>(xp0 + 4);
#pragma unroll
    for (int i = 0; i < 6; i++) {
      int tau = i * 4 + w; int n = 8 * tau + (l >> 3);
      GLD_LDS(wt + n * DIN + (l & 7) * 8, &wl[0][tau * 512]);
    }
    *reinterpret_cast<s16x8*>(&xl[0][xrow * 72 + xc * 8]) = pack8(xa, xb);
    asm volatile("s_waitcnt vmcnt(0)" ::: "memory");
    __syncthreads();
  }

  for (int ks = 0; ks < 12; ks++) {
    int cur = ks & 1;
    bool more = ks < 11;
    float4 na, nb;
    if (more) {
      int k1 = (ks + 1) * 64;
      na = *reinterpret_cast<const float4*>(xp0 + k1);
      nb = *reinterpret_cast<const float4*>(xp0 + k1 + 4);
#pragma unroll
      for (int i = 0; i < 6; i++) {
        int tau = i * 4 + w; int n = 8 * tau + (l >> 3);
        GLD_LDS(wt + n * DIN + k1 + (l & 7) * 8, &wl[cur ^ 1][tau * 512]);
      }
    }
    s16x8 a0 = ld8s(&xl[cur][(16 * wr + lq) * 72 + g * 8]);
    s16x8 a1 = ld8s(&xl[cur][(16 * wr + lq) * 72 + g * 8 + 32]);
#pragma unroll
    for (int nt = 0; nt < 6; nt++) {
      int n = wc * 96 + nt * 16 + lq;
      s16x8 b0 = ld8s(&wl[cur][n * 64 + ((g ^ (n & 7)) * 8)]);
      s16x8 b1 = ld8s(&wl[cur][n * 64 + (((g + 4) ^ (n & 7)) * 8)]);
      acc[nt] = __builtin_amdgcn_mfma_f32_16x16x32_bf16(a0, b0, acc[nt], 0, 0, 0);
      acc[nt] = __builtin_amdgcn_mfma_f32_16x16x32_bf16(a1, b1, acc[nt], 0, 0, 0);
    }
    if (more) {
      asm volatile("s_waitcnt vmcnt(0)" ::: "memory");
      *reinterpret_cast<s16x8*>(&xl[cur ^ 1][xrow * 72 + xc * 8]) = pack8(na, nb);
      __syncthreads();
    }
  }

  // epilogue
  int b = m0 >> 12;
  int srow0 = (m0 & (S_ - 1)) + 16 * wr + 4 * g;
#pragma unroll
  for (int nt = 0; nt < 6; nt++) {
    int col = wc * 96 + nt * 16 + lq;
    u16* base; int c;
    if (col < 64)       { base = qb; c = col; }
    else if (col < 128) { base = kb; c = col - 64; }
    else                { base = vt; c = col - 128; }
#pragma unroll
    for (int r = 0; r < 4; r++) {
      int srow = srow0 + r;
      u16 hv = f2bf(acc[nt][r]);
      if (col < 128) {
        int gr = (c >> 3) ^ (srow & 7);
        base[(size_t)(b * S_ + srow) * DH + gr * 8 + (c & 7)] = hv;
      } else {
        int gr = ((srow >> 3) & 7) ^ (c & 7);
        base[(size_t)(b * DH + c) * S_ + (srow & ~63) + gr * 8 + (srow & 7)] = hv;
      }
    }
  }
}

// ---------------- kernel 2: flash attention (swapped-QK^T lane-local softmax) ----
// 256 blocks of 512 thr (8 waves). Waves 0-3: kv 0..2047, waves 4-7: kv 2048..4095.
__global__ __launch_bounds__(512) void attn(const u16* __restrict__ qb,
    const u16* __restrict__ kb, const u16* __restrict__ vt, float* __restrict__ out) {
  __shared__ __align__(16) u16 smem[41984];

  int t = threadIdx.x;
  int w8 = t >> 6, half = w8 >> 2, w = w8 & 3, l = t & 63, g = l >> 4, lq = l & 15;
  int bq = blockIdx.x;
  int b = bq >> 6;
  int q0 = (bq & 63) * 64;
  int kvbase = half * 2048;

  // Q fragments (pre-scaled by 0.125 in projection)
  int sq = q0 + 16 * w + lq;
  const u16* qrow = qb + (size_t)(b * S_ + sq) * DH;
  s16x8 qa0 = ld8s(qrow + ((g ^ (sq & 7)) * 8));
  s16x8 qa1 = ld8s(qrow + (((g + 4) ^ (sq & 7)) * 8));

  u16* pl = smem + 32768 + w8 * 1152;

  // per-lane online-softmax state for q-row (16*w + lq); identical across g-copies
  float mrun = -1e30f, lrun = 0.f;
  f32x4 acco[4];
#pragma unroll
  for (int nt = 0; nt < 4; nt++) acco[nt] = f32x4{0.f, 0.f, 0.f, 0.f};

  int tau0 = w * 2;
  int srow_st = 8 * tau0 + (l >> 3);
  int gcol = (l & 7) * 8;

  // prologue: stage tile 0 into buf 0
  {
    u16* dst = smem + half * 16384;
#pragma unroll
    for (int i = 0; i < 2; i++) {
      int row = srow_st + 8 * i;
      GLD_LDS(kb + (size_t)(b * S_ + kvbase + row) * DH + gcol, &dst[(tau0 + i) * 512]);
      GLD_LDS(vt + (size_t)(b * DH + row) * S_ + kvbase + gcol, &dst[4096 + (tau0 + i) * 512]);
    }
    asm volatile("s_waitcnt vmcnt(0)" ::: "memory");
    __syncthreads();
  }

  const float L2E = 1.44269504f;

  for (int it = 0; it < 32; it++) {
    int cur = it & 1;
    bool more = it < 31;
    if (more) {
      int k1 = kvbase + (it + 1) * 64;
      u16* dst = smem + half * 16384 + (cur ^ 1) * 8192;
#pragma unroll
      for (int i = 0; i < 2; i++) {
        int row = srow_st + 8 * i;
        GLD_LDS(kb + (size_t)(b * S_ + k1 + row) * DH + gcol, &dst[(tau0 + i) * 512]);
        GLD_LDS(vt + (size_t)(b * DH + row) * S_ + k1 + gcol, &dst[4096 + (tau0 + i) * 512]);
      }
    }
    const u16* kl = smem + half * 16384 + cur * 8192;
    const u16* vl = kl + 4096;

    // S^T = K Q^T : D row = k = kt*16 + 4g + r, col = q = lq (swapped operands)
    f32x4 accs[4];
#pragma unroll
    for (int kt = 0; kt < 4; kt++) {
      int krow = kt * 16 + lq;
      s16x8 kf0 = ld8s(&kl[krow * 64 + ((g ^ (krow & 7)) * 8)]);
      s16x8 kf1 = ld8s(&kl[krow * 64 + (((g + 4) ^ (krow & 7)) * 8)]);
      f32x4 c = f32x4{0.f, 0.f, 0.f, 0.f};
      c = __builtin_amdgcn_mfma_f32_16x16x32_bf16(kf0, qa0, c, 0, 0, 0);
      c = __builtin_amdgcn_mfma_f32_16x16x32_bf16(kf1, qa1, c, 0, 0, 0);
      accs[kt] = c;
    }

    // lane-local softmax for q = lq: in-lane max over 16, 2 shfl_xor over g
    float mx = fmaxf(fmaxf(accs[0][0], accs[0][1]), fmaxf(accs[0][2], accs[0][3]));
#pragma unroll
    for (int kt = 1; kt < 4; kt++)
      mx = fmaxf(mx, fmaxf(fmaxf(accs[kt][0], accs[kt][1]),
                           fmaxf(accs[kt][2], accs[kt][3])));
    mx = fmaxf(mx, __shfl_xor(mx, 16));
    mx = fmaxf(mx, __shfl_xor(mx, 32));
    float mnew = fmaxf(mrun, mx);
    float scale = exp2f((mrun - mnew) * L2E);
    // broadcast rescale factors for O rows q = 4g+r (independent bpermutes)
    float sc0 = __shfl(scale, 4 * g + 0);
    float sc1 = __shfl(scale, 4 * g + 1);
    float sc2 = __shfl(scale, 4 * g + 2);
    float sc3 = __shfl(scale, 4 * g + 3);

    float s = 0.f;
#pragma unroll
    for (int kt = 0; kt < 4; kt++) {
#pragma unroll
      for (int r = 0; r < 4; r++) {
        float e = exp2f((accs[kt][r] - mnew) * L2E);
        accs[kt][r] = e; s += e;
      }
    }
    s += __shfl_xor(s, 16);
    s += __shfl_xor(s, 32);
    lrun = lrun * scale + s;
    mrun = mnew;

    // P -> per-wave LDS, transposed to [q][k]: 4x ds_write_b64
#pragma unroll
    for (int kt = 0; kt < 4; kt++) {
      uint2 u;
      u.x = bfpack2(accs[kt][0], accs[kt][1]);
      u.y = bfpack2(accs[kt][2], accs[kt][3]);
      *reinterpret_cast<uint2*>(&pl[lq * 72 + kt * 16 + 4 * g]) = u;
    }
    asm volatile("s_waitcnt lgkmcnt(0)" ::: "memory");

    // rescale O accumulator (row q = 4g+r)
#pragma unroll
    for (int nt = 0; nt < 4; nt++) {
      acco[nt][0] *= sc0; acco[nt][1] *= sc1;
      acco[nt][2] *= sc2; acco[nt][3] *= sc3;
    }

    s16x8 pa0 = ld8s(&pl[lq * 72 + g * 8]);
    s16x8 pa1 = ld8s(&pl[lq * 72 + 32 + g * 8]);
#pragma unroll
    for (int nt = 0; nt < 4; nt++) {
      int d = nt * 16 + lq;
      s16x8 vf0 = ld8s(&vl[d * 64 + ((g ^ (d & 7)) * 8)]);
      s16x8 vf1 = ld8s(&vl[d * 64 + (((g + 4) ^ (d & 7)) * 8)]);
      acco[nt] = __builtin_amdgcn_mfma_f32_16x16x32_bf16(pa0, vf0, acco[nt], 0, 0, 0);
      acco[nt] = __builtin_amdgcn_mfma_f32_16x16x32_bf16(pa1, vf1, acco[nt], 0, 0, 0);
    }
    if (more) {
      asm volatile("s_waitcnt vmcnt(0)" ::: "memory");
      __syncthreads();
    }
  }

  // ---- merge the two kv halves ----
  __syncthreads();
  float* mO = reinterpret_cast<float*>(smem);          // 64*64 f32
  float* mM = reinterpret_cast<float*>(smem) + 4096;   // 64
  float* mL = mM + 64;                                 // 64

  if (half == 1) {
#pragma unroll
    for (int nt = 0; nt < 4; nt++)
#pragma unroll
      for (int r = 0; r < 4; r++)
        mO[(16 * w + 4 * g + r) * 64 + nt * 16 + lq] = acco[nt][r];
    if (g == 0) {
      mM[16 * w + lq] = mrun;
      mL[16 * w + lq] = lrun;
    }
  }
  __syncthreads();
  if (half == 0) {
#pragma unroll
    for (int r = 0; r < 4; r++) {
      int row = 16 * w + 4 * g + r;
      float m1 = __shfl(mrun, 4 * g + r);
      float l1 = __shfl(lrun, 4 * g + r);
      float m2 = mM[row], l2 = mL[row];
      float m = fmaxf(m1, m2);
      float f1 = exp2f((m1 - m) * 1.44269504f);
      float f2 = exp2f((m2 - m) * 1.44269504f);
      float inv = 1.0f / (l1 * f1 + l2 * f2);
#pragma unroll
      for (int nt = 0; nt < 4; nt++) {
        float val = (acco[nt][r] * f1 + mO[row * 64 + nt * 16 + lq] * f2) * inv;
        out[(size_t)(b * S_ + q0 + row) * DH + nt * 16 + lq] = val;
      }
    }
  }
}

extern "C" void kernel_launch(void* const* d_in, const int* in_sizes, int n_in,
                              void* d_out, int out_size, void* d_ws, size_t ws_size,
                              hipStream_t stream) {
  const float* x  = (const float*)d_in[0];
  const float* wq = (const float*)d_in[1];
  const float* wk = (const float*)d_in[2];
  const float* wv = (const float*)d_in[3];
  float* out = (float*)d_out;
  char* ws = (char*)d_ws;

  u16* wt = (u16*)(ws);
  u16* qb = (u16*)(ws + 294912);
  u16* kb = (u16*)(ws + 294912 + 2097152);
  u16* vt = (u16*)(ws + 294912 + 2 * 2097152);

  hipLaunchKernelGGL(prep_w,   dim3(576), dim3(256), 0, stream, wq, wk, wv, wt);
  hipLaunchKernelGGL(qkv_gemm, dim3(512), dim3(256), 0, stream, x, wt, qb, kb, vt);
  hipLaunchKernelGGL(attn,     dim3(256), dim3(512), 0, stream, qb, kb, vt, out);
}